// Round 2
// baseline (1389.359 us; speedup 1.0000x reference)
//
#include <hip/hip_runtime.h>
#include <cstdint>

typedef __attribute__((ext_vector_type(8))) short short8;
typedef __attribute__((ext_vector_type(4))) float floatx4;

#define TSEQ 256
#define TDEC 180
#define NIN  6
#define GROWS 8
#define NBLK (4096 / GROWS)

// split fp32 into hi/lo bf16 (truncation both times): x ~= hi + lo, err ~2^-16*|x|
__device__ __forceinline__ void split2(float x, uint16_t &h, uint16_t &l) {
  uint32_t u = __float_as_uint(x);
  h = (uint16_t)(u >> 16);
  float hf = __uint_as_float(u & 0xffff0000u);
  l = (uint16_t)(__float_as_uint(x - hf) >> 16);
}

__device__ __forceinline__ floatx4 mfma16(short8 a, short8 b, floatx4 c) {
  return __builtin_amdgcn_mfma_f32_16x16x32_bf16(a, b, c, 0, 0, 0);
}

__device__ __forceinline__ float sigm(float v) {
  return __builtin_amdgcn_rcpf(1.0f + __builtin_amdgcn_exp2f(-1.4426950408889634f * v));
}
__device__ __forceinline__ float tanh_fast(float v) {
  return 2.0f * __builtin_amdgcn_rcpf(1.0f + __builtin_amdgcn_exp2f(-2.8853900817779268f * v)) - 1.0f;
}

__global__ void __launch_bounds__(256, 2)
gru_persist(const float* __restrict__ x,
            const float* __restrict__ eWih0, const float* __restrict__ eWhh0,
            const float* __restrict__ ebih0, const float* __restrict__ ebhh0,
            const float* __restrict__ eWih1, const float* __restrict__ eWhh1,
            const float* __restrict__ ebih1, const float* __restrict__ ebhh1,
            const float* __restrict__ dWih0, const float* __restrict__ dWhh0,
            const float* __restrict__ dbih0, const float* __restrict__ dbhh0,
            const float* __restrict__ dWih1, const float* __restrict__ dWhh1,
            const float* __restrict__ dbih1, const float* __restrict__ dbhh1,
            const float* __restrict__ outW, const float* __restrict__ outB,
            float* __restrict__ out)
{
  // h0 staging rows: cols 0..63 = h0, 64..69 = x_t (enc), 70..95 = zeros, 96..103 pad
  // row stride 104 elems (208B): 16B-aligned rows, 2-way LDS banking on b128 reads (free)
  __shared__ __align__(16) uint16_t s0h[2][16][104];
  __shared__ __align__(16) uint16_t s0l[2][16][104];
  __shared__ __align__(16) uint16_t s1h[2][16][72];
  __shared__ __align__(16) uint16_t s1l[2][16][72];
  __shared__ float cvp[2][16][4];

  const int tid  = threadIdx.x;
  const int wv   = tid >> 6;       // wave 0..3: owns tiles {wv, wv+4, wv+8} => u-range wv*16..wv*16+15
  const int lane = tid & 63;
  const int c    = lane & 15;      // MFMA: A row m / B,D col n
  const int q    = lane >> 4;      // quad
  const long base = (long)blockIdx.x * GROWS;

  // zero all staging (A rows 8..15 and cols 70..95 must be finite; junk rows stay bounded)
  for (int i = tid; i < 2 * 16 * 104; i += 256) { ((uint16_t*)s0h)[i] = 0; ((uint16_t*)s0l)[i] = 0; }
  for (int i = tid; i < 2 * 16 * 72;  i += 256) { ((uint16_t*)s1h)[i] = 0; ((uint16_t*)s1l)[i] = 0; }
  // x_0 into parity 0 (8 real rows)
  if (tid < GROWS * NIN) {
    int m = tid / 6, i = tid - m * 6;
    uint16_t h, l; split2(x[(base + m) * (TSEQ * NIN) + i], h, l);
    s0h[0][m][64 + i] = h; s0l[0][m][64 + i] = l;
  }

  // register-resident B fragments (hi/lo): [slot][kt]
  short8 B0h[3][3],  B0l[3][3];     // layer0: [Whh0 | Wih0-as-kt2 (encoder only)]
  short8 B1ih[3][2], B1il[3][2];    // layer1 input weights
  short8 B1hh[3][2], B1hl[3][2];    // layer1 recurrent weights
  short8 BFh[3][2],  BFl[3][2];     // decoder head-fold: W' = dWih0 (.) outW^T (rank-1)
  float bc_r, bc_z, bi_n, bh_n, bc1r, bc1z, bi1n, bh1n;

  auto load_phase = [&](const float* Whh0, const float* WihX, const float* Wih1,
                        const float* Whh1, bool enc) {
    #pragma unroll
    for (int s = 0; s < 3; s++) {
      const int n = (s * 4 + wv) * 16 + c;  // B col = j index in [0,192)
      #pragma unroll
      for (int kt = 0; kt < 2; kt++) {
        const int k0 = kt * 32 + q * 8;
        #pragma unroll
        for (int j = 0; j < 8; j++) {
          uint16_t h, l;
          split2(Whh0[n * 64 + k0 + j], h, l); B0h[s][kt][j]  = (short)h; B0l[s][kt][j]  = (short)l;
          split2(Wih1[n * 64 + k0 + j], h, l); B1ih[s][kt][j] = (short)h; B1il[s][kt][j] = (short)l;
          split2(Whh1[n * 64 + k0 + j], h, l); B1hh[s][kt][j] = (short)h; B1hl[s][kt][j] = (short)l;
        }
      }
      if (enc) {
        // kt=2: rows k=64.. hold the encoder layer-0 input weights (x: 6 cols), rest zero
        #pragma unroll
        for (int j = 0; j < 8; j++) {
          float v = (q == 0 && j < NIN) ? WihX[n * NIN + j] : 0.0f;
          uint16_t h, l; split2(v, h, l);
          B0h[s][2][j] = (short)h; B0l[s][2][j] = (short)l;
        }
      }
    }
  };
  auto load_bias = [&](const float* bi0, const float* bh0, const float* bi1, const float* bh1) {
    const int jr = wv * 16 + c;
    bc_r = bi0[jr] + bh0[jr];
    bc_z = bi0[64 + jr] + bh0[64 + jr];
    bi_n = bi0[128 + jr]; bh_n = bh0[128 + jr];
    bc1r = bi1[jr] + bh1[jr];
    bc1z = bi1[64 + jr] + bh1[64 + jr];
    bi1n = bi1[128 + jr]; bh1n = bh1[128 + jr];
  };

  load_phase(eWhh0, eWih0, eWih1, eWhh1, true);
  load_bias(ebih0, ebhh0, ebih1, ebhh1);
  const float woutr = outW[wv * 16 + c];
  const float ob = outB[0];
  float h0r[4] = {0, 0, 0, 0}, h1r[4] = {0, 0, 0, 0};
  __syncthreads();

  // ============================ encoder ============================
  for (int t = 0; t < TSEQ; t++) {
    const int p = t & 1, pn = p ^ 1;

    float xpre = 0.0f; int xm = 0, xi = 0;
    if (tid < GROWS * NIN) {  // prefetch x_{t+1}
      xm = tid / 6; xi = tid - xm * 6;
      if (t + 1 < TSEQ) xpre = x[(base + xm) * (TSEQ * NIN) + (t + 1) * NIN + xi];
    }

    // ---- layer 0: [h0 | x_t] @ [Whh0 | Wih0]^T  (K=96 in 3 kt-tiles) ----
    floatx4 ar  = {bc_r, bc_r, bc_r, bc_r};
    floatx4 az  = {bc_z, bc_z, bc_z, bc_z};
    floatx4 agh = {bh_n, bh_n, bh_n, bh_n};   // gh_n (recurrent part, gets bhh_n)
    floatx4 agi = {bi_n, bi_n, bi_n, bi_n};   // gi_n (input part, gets bih_n)
    #pragma unroll
    for (int kt = 0; kt < 3; kt++) {
      const int kb = kt * 32 + q * 8;
      const short8 ah = *(const short8*)&s0h[p][c][kb];
      const short8 al = *(const short8*)&s0l[p][c][kb];
      ar = mfma16(ah, B0h[0][kt], ar); ar = mfma16(al, B0h[0][kt], ar); ar = mfma16(ah, B0l[0][kt], ar);
      az = mfma16(ah, B0h[1][kt], az); az = mfma16(al, B0h[1][kt], az); az = mfma16(ah, B0l[1][kt], az);
      if (kt < 2) { agh = mfma16(ah, B0h[2][kt], agh); agh = mfma16(al, B0h[2][kt], agh); agh = mfma16(ah, B0l[2][kt], agh); }
      else        { agi = mfma16(ah, B0h[2][kt], agi); agi = mfma16(al, B0h[2][kt], agi); agi = mfma16(ah, B0l[2][kt], agi); }
    }
    #pragma unroll
    for (int r4 = 0; r4 < 4; r4++) {
      const float rr = sigm(ar[r4]);
      const float zz = sigm(az[r4]);
      const float nn = tanh_fast(agi[r4] + rr * agh[r4]);
      const float hn = nn + zz * (h0r[r4] - nn);
      h0r[r4] = hn;
      uint16_t hh, hl; split2(hn, hh, hl);
      s0h[pn][q * 4 + r4][wv * 16 + c] = hh;
      s0l[pn][q * 4 + r4][wv * 16 + c] = hl;
    }
    __syncthreads();  // h0' visible for layer-1 gi

    // ---- layer 1: gi from h0' (parity pn), gh from h1 (parity p) ----
    floatx4 b_r = {bc1r, bc1r, bc1r, bc1r};
    floatx4 b_z = {bc1z, bc1z, bc1z, bc1z};
    floatx4 bgi = {bi1n, bi1n, bi1n, bi1n};
    floatx4 bgh = {bh1n, bh1n, bh1n, bh1n};
    #pragma unroll
    for (int kt = 0; kt < 2; kt++) {
      const int kb = kt * 32 + q * 8;
      const short8 ah = *(const short8*)&s0h[pn][c][kb];
      const short8 al = *(const short8*)&s0l[pn][c][kb];
      b_r = mfma16(ah, B1ih[0][kt], b_r); b_r = mfma16(al, B1ih[0][kt], b_r); b_r = mfma16(ah, B1il[0][kt], b_r);
      b_z = mfma16(ah, B1ih[1][kt], b_z); b_z = mfma16(al, B1ih[1][kt], b_z); b_z = mfma16(ah, B1il[1][kt], b_z);
      bgi = mfma16(ah, B1ih[2][kt], bgi); bgi = mfma16(al, B1ih[2][kt], bgi); bgi = mfma16(ah, B1il[2][kt], bgi);
      const short8 gh_ = *(const short8*)&s1h[p][c][kb];
      const short8 gl_ = *(const short8*)&s1l[p][c][kb];
      b_r = mfma16(gh_, B1hh[0][kt], b_r); b_r = mfma16(gl_, B1hh[0][kt], b_r); b_r = mfma16(gh_, B1hl[0][kt], b_r);
      b_z = mfma16(gh_, B1hh[1][kt], b_z); b_z = mfma16(gl_, B1hh[1][kt], b_z); b_z = mfma16(gh_, B1hl[1][kt], b_z);
      bgh = mfma16(gh_, B1hh[2][kt], bgh); bgh = mfma16(gl_, B1hh[2][kt], bgh); bgh = mfma16(gh_, B1hl[2][kt], bgh);
    }
    #pragma unroll
    for (int r4 = 0; r4 < 4; r4++) {
      const float rr = sigm(b_r[r4]);
      const float zz = sigm(b_z[r4]);
      const float nn = tanh_fast(bgi[r4] + rr * bgh[r4]);
      const float hn = nn + zz * (h1r[r4] - nn);
      h1r[r4] = hn;
      uint16_t hh, hl; split2(hn, hh, hl);
      s1h[pn][q * 4 + r4][wv * 16 + c] = hh;
      s1l[pn][q * 4 + r4][wv * 16 + c] = hl;
    }
    if (tid < GROWS * NIN) {  // stage x_{t+1} into next parity
      uint16_t hh, hl; split2(xpre, hh, hl);
      s0h[pn][xm][64 + xi] = hh; s0l[pn][xm][64 + xi] = hl;
    }
    __syncthreads();
  }

  // ============================ decoder ============================
  // Head fold: prev(t) = outW.h1(t-1) + ob  =>  Wih0.prev = (dWih0 outW^T).h1(t-1) + dWih0*ob.
  // Layer0 consumes h1(t-1) directly from s1[p] via rank-1 W' fragments; no feedback barrier.
  load_phase(dWhh0, dWih0, dWih1, dWhh1, false);
  load_bias(dbih0, dbhh0, dbih1, dbhh1);
  float fo_r, fo_z, fo_n;
  {
    const int jr = wv * 16 + c;
    fo_r = dWih0[jr] * ob;
    fo_z = dWih0[64 + jr] * ob;
    fo_n = dWih0[128 + jr] * ob;
    #pragma unroll
    for (int s = 0; s < 3; s++) {
      const int n = (s * 4 + wv) * 16 + c;
      const float wd = dWih0[n];
      #pragma unroll
      for (int kt = 0; kt < 2; kt++) {
        const int k0 = kt * 32 + q * 8;
        #pragma unroll
        for (int j = 0; j < 8; j++) {
          uint16_t h, l; split2(wd * outW[k0 + j], h, l);
          BFh[s][kt][j] = (short)h; BFl[s][kt][j] = (short)l;
        }
      }
    }
  }
  __syncthreads();

  for (int t = TSEQ; t < TSEQ + TDEC; t++) {
    const int p = t & 1, pn = p ^ 1;
    const bool useF = (t != TSEQ);   // first decoder step: prev = 0 (no fold terms)

    // ---- layer 0: Whh0.h0(t-1) + W'.h1(t-1) + consts ----
    const float cr = useF ? bc_r + fo_r : bc_r;
    const float cz = useF ? bc_z + fo_z : bc_z;
    const float cn = useF ? bi_n + fo_n : bi_n;
    floatx4 ar  = {cr, cr, cr, cr};
    floatx4 az  = {cz, cz, cz, cz};
    floatx4 agh = {bh_n, bh_n, bh_n, bh_n};
    floatx4 agi = {cn, cn, cn, cn};
    #pragma unroll
    for (int kt = 0; kt < 2; kt++) {
      const int kb = kt * 32 + q * 8;
      const short8 ah = *(const short8*)&s0h[p][c][kb];
      const short8 al = *(const short8*)&s0l[p][c][kb];
      ar = mfma16(ah, B0h[0][kt], ar); ar = mfma16(al, B0h[0][kt], ar); ar = mfma16(ah, B0l[0][kt], ar);
      az = mfma16(ah, B0h[1][kt], az); az = mfma16(al, B0h[1][kt], az); az = mfma16(ah, B0l[1][kt], az);
      agh = mfma16(ah, B0h[2][kt], agh); agh = mfma16(al, B0h[2][kt], agh); agh = mfma16(ah, B0l[2][kt], agh);
    }
    if (useF) {
      #pragma unroll
      for (int kt = 0; kt < 2; kt++) {
        const int kb = kt * 32 + q * 8;
        const short8 fh = *(const short8*)&s1h[p][c][kb];
        const short8 fl = *(const short8*)&s1l[p][c][kb];
        ar  = mfma16(fh, BFh[0][kt], ar);  ar  = mfma16(fl, BFh[0][kt], ar);  ar  = mfma16(fh, BFl[0][kt], ar);
        az  = mfma16(fh, BFh[1][kt], az);  az  = mfma16(fl, BFh[1][kt], az);  az  = mfma16(fh, BFl[1][kt], az);
        agi = mfma16(fh, BFh[2][kt], agi); agi = mfma16(fl, BFh[2][kt], agi); agi = mfma16(fh, BFl[2][kt], agi);
      }
    }
    #pragma unroll
    for (int r4 = 0; r4 < 4; r4++) {
      const float rr = sigm(ar[r4]);
      const float zz = sigm(az[r4]);
      const float nn = tanh_fast(agi[r4] + rr * agh[r4]);
      const float hn = nn + zz * (h0r[r4] - nn);
      h0r[r4] = hn;
      uint16_t hh, hl; split2(hn, hh, hl);
      s0h[pn][q * 4 + r4][wv * 16 + c] = hh;
      s0l[pn][q * 4 + r4][wv * 16 + c] = hl;
    }
    __syncthreads();

    // ---- layer 1 ----
    floatx4 b_r = {bc1r, bc1r, bc1r, bc1r};
    floatx4 b_z = {bc1z, bc1z, bc1z, bc1z};
    floatx4 bgi = {bi1n, bi1n, bi1n, bi1n};
    floatx4 bgh = {bh1n, bh1n, bh1n, bh1n};
    #pragma unroll
    for (int kt = 0; kt < 2; kt++) {
      const int kb = kt * 32 + q * 8;
      const short8 ah = *(const short8*)&s0h[pn][c][kb];
      const short8 al = *(const short8*)&s0l[pn][c][kb];
      b_r = mfma16(ah, B1ih[0][kt], b_r); b_r = mfma16(al, B1ih[0][kt], b_r); b_r = mfma16(ah, B1il[0][kt], b_r);
      b_z = mfma16(ah, B1ih[1][kt], b_z); b_z = mfma16(al, B1ih[1][kt], b_z); b_z = mfma16(ah, B1il[1][kt], b_z);
      bgi = mfma16(ah, B1ih[2][kt], bgi); bgi = mfma16(al, B1ih[2][kt], bgi); bgi = mfma16(ah, B1il[2][kt], bgi);
      const short8 gh_ = *(const short8*)&s1h[p][c][kb];
      const short8 gl_ = *(const short8*)&s1l[p][c][kb];
      b_r = mfma16(gh_, B1hh[0][kt], b_r); b_r = mfma16(gl_, B1hh[0][kt], b_r); b_r = mfma16(gh_, B1hl[0][kt], b_r);
      b_z = mfma16(gh_, B1hh[1][kt], b_z); b_z = mfma16(gl_, B1hh[1][kt], b_z); b_z = mfma16(gh_, B1hl[1][kt], b_z);
      bgh = mfma16(gh_, B1hh[2][kt], bgh); bgh = mfma16(gl_, B1hh[2][kt], bgh); bgh = mfma16(gh_, B1hl[2][kt], bgh);
    }
    #pragma unroll
    for (int r4 = 0; r4 < 4; r4++) {
      const float rr = sigm(b_r[r4]);
      const float zz = sigm(b_z[r4]);
      const float nn = tanh_fast(bgi[r4] + rr * bgh[r4]);
      const float hn = nn + zz * (h1r[r4] - nn);
      h1r[r4] = hn;
      uint16_t hh, hl; split2(hn, hh, hl);
      s1h[pn][q * 4 + r4][wv * 16 + c] = hh;
      s1l[pn][q * 4 + r4][wv * 16 + c] = hl;
      // per-wave partial of cv = sum_u h1'[m][u]*outW[u]
      float v = hn * woutr;
      v += __shfl_xor(v, 1, 16);
      v += __shfl_xor(v, 2, 16);
      v += __shfl_xor(v, 4, 16);
      v += __shfl_xor(v, 8, 16);
      if (c == 0) cvp[p][q * 4 + r4][wv] = v;
    }
    __syncthreads();
    // off-critical-path: nothing below feeds the recurrence (head is folded)
    if (tid < GROWS) {
      out[(base + tid) * TDEC + (t - TSEQ)] =
          ob + cvp[p][tid][0] + cvp[p][tid][1] + cvp[p][tid][2] + cvp[p][tid][3];
    }
  }
}

extern "C" void kernel_launch(void* const* d_in, const int* in_sizes, int n_in,
                              void* d_out, int out_size, void* d_ws, size_t ws_size,
                              hipStream_t stream) {
  (void)in_sizes; (void)n_in; (void)d_ws; (void)ws_size; (void)out_size;
  const float* x     = (const float*)d_in[0];
  const float* eWih0 = (const float*)d_in[1];
  const float* eWhh0 = (const float*)d_in[2];
  const float* ebih0 = (const float*)d_in[3];
  const float* ebhh0 = (const float*)d_in[4];
  const float* eWih1 = (const float*)d_in[5];
  const float* eWhh1 = (const float*)d_in[6];
  const float* ebih1 = (const float*)d_in[7];
  const float* ebhh1 = (const float*)d_in[8];
  const float* dWih0 = (const float*)d_in[9];
  const float* dWhh0 = (const float*)d_in[10];
  const float* dbih0 = (const float*)d_in[11];
  const float* dbhh0 = (const float*)d_in[12];
  const float* dWih1 = (const float*)d_in[13];
  const float* dWhh1 = (const float*)d_in[14];
  const float* dbih1 = (const float*)d_in[15];
  const float* dbhh1 = (const float*)d_in[16];
  const float* outW  = (const float*)d_in[17];
  const float* outB  = (const float*)d_in[18];
  hipLaunchKernelGGL(gru_persist, dim3(NBLK), dim3(256), 0, stream,
                     x, eWih0, eWhh0, ebih0, ebhh0, eWih1, eWhh1, ebih1, ebhh1,
                     dWih0, dWhh0, dbih0, dbhh0, dWih1, dWhh1, dbih1, dbhh1,
                     outW, outB, (float*)d_out);
}

// Round 3
// 673.441 us; speedup vs baseline: 2.0631x; 2.0631x over previous
//
#include <hip/hip_runtime.h>
#include <cstdint>

typedef __attribute__((ext_vector_type(8))) short short8;
typedef __attribute__((ext_vector_type(4))) float floatx4;

#define TSEQ 256
#define TDEC 180
#define NIN  6
#define GROWS 16
#define NBLK (4096 / GROWS)
#define RS0 104   // s0 row stride (shorts): cols 0..63 h0, 64..95 x|0, 96..103 pad
#define RS1 72    // s1 row stride

// split fp32 into hi/lo bf16 (truncation): x ~= hi + lo, err ~2^-16*|x|
__device__ __forceinline__ void split2(float x, uint16_t &h, uint16_t &l) {
  uint32_t u = __float_as_uint(x);
  h = (uint16_t)(u >> 16);
  float hf = __uint_as_float(u & 0xffff0000u);
  l = (uint16_t)(__float_as_uint(x - hf) >> 16);
}

__device__ __forceinline__ floatx4 mfma16(short8 a, short8 b, floatx4 c) {
  return __builtin_amdgcn_mfma_f32_16x16x32_bf16(a, b, c, 0, 0, 0);
}

__device__ __forceinline__ float sigm(float v) {
  return __builtin_amdgcn_rcpf(1.0f + __builtin_amdgcn_exp2f(-1.4426950408889634f * v));
}
__device__ __forceinline__ float tanh_fast(float v) {
  return 2.0f * __builtin_amdgcn_rcpf(1.0f + __builtin_amdgcn_exp2f(-2.8853900817779268f * v)) - 1.0f;
}

// 2-ktile 3-accumulator split-bf16 pass: acc += [Ah|Al] @ [Wh|Wl] (3-term product)
#define PASS2(SH, SL, r, z, g, Wh, Wl) do {                                              \
    _Pragma("unroll")                                                                    \
    for (int kt_ = 0; kt_ < 2; kt_++) {                                                  \
      const short8 ah_ = *(const short8*)((SH) + kt_ * 32);                              \
      const short8 al_ = *(const short8*)((SL) + kt_ * 32);                              \
      r = mfma16(ah_, (Wh)[0][kt_], r); r = mfma16(al_, (Wh)[0][kt_], r); r = mfma16(ah_, (Wl)[0][kt_], r); \
      z = mfma16(ah_, (Wh)[1][kt_], z); z = mfma16(al_, (Wh)[1][kt_], z); z = mfma16(ah_, (Wl)[1][kt_], z); \
      g = mfma16(ah_, (Wh)[2][kt_], g); g = mfma16(al_, (Wh)[2][kt_], g); g = mfma16(ah_, (Wl)[2][kt_], g); \
    } } while (0)

#define PASS1(SH, SL, r, z, g, Wh, Wl) do {                                              \
      const short8 ah_ = *(const short8*)(SH);                                           \
      const short8 al_ = *(const short8*)(SL);                                           \
      r = mfma16(ah_, (Wh)[0][0], r); r = mfma16(al_, (Wh)[0][0], r); r = mfma16(ah_, (Wl)[0][0], r); \
      z = mfma16(ah_, (Wh)[1][0], z); z = mfma16(al_, (Wh)[1][0], z); z = mfma16(ah_, (Wl)[1][0], z); \
      g = mfma16(ah_, (Wh)[2][0], g); g = mfma16(al_, (Wh)[2][0], g); g = mfma16(ah_, (Wl)[2][0], g); \
    } while (0)

__global__ void __launch_bounds__(512, 2)
gru_persist(const float* __restrict__ x,
            const float* __restrict__ eWih0, const float* __restrict__ eWhh0,
            const float* __restrict__ ebih0, const float* __restrict__ ebhh0,
            const float* __restrict__ eWih1, const float* __restrict__ eWhh1,
            const float* __restrict__ ebih1, const float* __restrict__ ebhh1,
            const float* __restrict__ dWih0, const float* __restrict__ dWhh0,
            const float* __restrict__ dbih0, const float* __restrict__ dbhh0,
            const float* __restrict__ dWih1, const float* __restrict__ dWhh1,
            const float* __restrict__ dbih1, const float* __restrict__ dbhh1,
            const float* __restrict__ outW, const float* __restrict__ outB,
            float* __restrict__ out)
{
  __shared__ __align__(16) uint16_t s0h[2][16][RS0], s0l[2][16][RS0];
  __shared__ __align__(16) uint16_t s1h[2][16][RS1], s1l[2][16][RS1];
  __shared__ float cvp[2][16][4];

  const int tid  = threadIdx.x;
  const bool isA = tid < 256;          // group A = layer0 waves, group B = layer1 waves
  const int wvL  = (tid >> 6) & 3;     // wave index within group
  const int lane = tid & 63;
  const int c    = lane & 15;          // MFMA A-row m / B,D-col n
  const int q    = lane >> 4;          // quad
  const int u    = wvL * 16 + c;       // owned hidden unit
  const long base = (long)blockIdx.x * GROWS;

  for (int i = tid; i < 2 * 16 * RS0; i += 512) { ((uint16_t*)s0h)[i] = 0; ((uint16_t*)s0l)[i] = 0; }
  for (int i = tid; i < 2 * 16 * RS1; i += 512) { ((uint16_t*)s1h)[i] = 0; ((uint16_t*)s1l)[i] = 0; }
  if (tid < GROWS * NIN) {  // x(0) -> s0[0]
    int m = tid / 6, i2 = tid - m * 6;
    uint16_t h, l; split2(x[(base + m) * (TSEQ * NIN) + i2], h, l);
    s0h[0][m][64 + i2] = h; s0l[0][m][64 + i2] = l;
  }

  // shared-variable weight fragments: each wave holds ONLY its group's weights here
  short8 W1h[3][2], W1l[3][2];   // src1-side (s0/h0 input): A: Whh0, B: Wih1
  short8 W2h[3][2], W2l[3][2];   // src2-side: A: [Wih0|0] (enc) / fold (dec), B: Whh1
  float cR, cZ, c3, c4;          // accumulator init consts (group-specific values)
  float hr[4] = {0, 0, 0, 0};    // A: h0 state, B: h1 state
  floatx4 aR, aZ, a3, a4;        // shared accumulators (src1 3rd acc = a3, src2 3rd = a4)
  float woutr = 0.0f, ob = 0.0f;

  uint16_t* dstH = isA ? &s0h[0][0][0] : &s1h[0][0][0];
  uint16_t* dstL = isA ? &s0l[0][0][0] : &s1l[0][0][0];
  const int dRS  = isA ? RS0 : RS1;

  auto loadW64 = [&](const float* W) {
    #pragma unroll
    for (int s = 0; s < 3; s++) {
      const int n = (s * 4 + wvL) * 16 + c;
      #pragma unroll
      for (int kt = 0; kt < 2; kt++) {
        const int k0 = kt * 32 + q * 8;
        #pragma unroll
        for (int j = 0; j < 8; j++) {
          uint16_t h, l; split2(W[n * 64 + k0 + j], h, l);
          W1h[s][kt][j] = (short)h; W1l[s][kt][j] = (short)l;
        }
      }
    }
  };
  auto loadW64b = [&](const float* W) {
    #pragma unroll
    for (int s = 0; s < 3; s++) {
      const int n = (s * 4 + wvL) * 16 + c;
      #pragma unroll
      for (int kt = 0; kt < 2; kt++) {
        const int k0 = kt * 32 + q * 8;
        #pragma unroll
        for (int j = 0; j < 8; j++) {
          uint16_t h, l; split2(W[n * 64 + k0 + j], h, l);
          W2h[s][kt][j] = (short)h; W2l[s][kt][j] = (short)l;
        }
      }
    }
  };

  // gate combine + state update + h write (+ optional head partial)
  auto epi = [&](int pn, bool doHead, int ph) {
    #pragma unroll
    for (int r4 = 0; r4 < 4; r4++) {
      const float gr = sigm(aR[r4]);
      const float gz = sigm(aZ[r4]);
      const float gi = isA ? a4[r4] : a3[r4];   // A: gi from src2(x/fold); B: gi from src1(ih)
      const float gh = isA ? a3[r4] : a4[r4];
      const float nn = tanh_fast(gi + gr * gh);
      const float hn = nn + gz * (hr[r4] - nn);
      hr[r4] = hn;
      uint16_t hh, hl; split2(hn, hh, hl);
      const int off = pn * 16 * dRS + (q * 4 + r4) * dRS + u;
      dstH[off] = hh; dstL[off] = hl;
      if (doHead) {
        float v = hn * woutr;
        v += __shfl_xor(v, 1, 16); v += __shfl_xor(v, 2, 16);
        v += __shfl_xor(v, 4, 16); v += __shfl_xor(v, 8, 16);
        if (c == 0) cvp[ph][q * 4 + r4][wvL] = v;
      }
    }
  };

  // ---- encoder weights/consts (divergent load into shared vars) ----
  if (isA) {
    loadW64(eWhh0);
    #pragma unroll
    for (int s = 0; s < 3; s++) {
      const int n = (s * 4 + wvL) * 16 + c;
      #pragma unroll
      for (int kt = 0; kt < 2; kt++)
        #pragma unroll
        for (int j = 0; j < 8; j++) {
          float v = (kt == 0 && q == 0 && j < NIN) ? eWih0[n * NIN + j] : 0.0f;
          uint16_t h, l; split2(v, h, l);
          W2h[s][kt][j] = (short)h; W2l[s][kt][j] = (short)l;
        }
    }
    cR = ebih0[u] + ebhh0[u];
    cZ = ebih0[64 + u] + ebhh0[64 + u];
    c3 = ebhh0[128 + u];   // gh const (src1 = Whh0)
    c4 = ebih0[128 + u];   // gi const (src2 = x)
  } else {
    loadW64(eWih1); loadW64b(eWhh1);
    cR = ebih1[u] + ebhh1[u];
    cZ = ebih1[64 + u] + ebhh1[64 + u];
    c3 = ebih1[128 + u];   // gi const (src1 = ih)
    c4 = ebhh1[128 + u];   // gh const (src2 = hh)
  }
  __syncthreads();

  // ============================ encoder: 1 barrier/iter, B skewed -1 ============================
  for (int i = 0; i <= TSEQ; i++) {
    const int p = i & 1, pn = p ^ 1;
    const bool active = isA ? (i < TSEQ) : (i > 0);
    float xpre = 0.0f; int xm = 0, xi = 0;
    const bool doX = (tid < GROWS * NIN) && (i + 1 < TSEQ);
    if (doX) {
      xm = tid / 6; xi = tid - xm * 6;
      xpre = x[(base + xm) * (TSEQ * NIN) + (i + 1) * NIN + xi];
    }
    if (active) {
      aR = (floatx4){cR, cR, cR, cR}; aZ = (floatx4){cZ, cZ, cZ, cZ};
      a3 = (floatx4){c3, c3, c3, c3}; a4 = (floatx4){c4, c4, c4, c4};
      PASS2(&s0h[p][c][q * 8], &s0l[p][c][q * 8], aR, aZ, a3, W1h, W1l);
      if (isA) {
        PASS1(&s0h[p][c][64 + q * 8], &s0l[p][c][64 + q * 8], aR, aZ, a4, W2h, W2l);
      } else {
        PASS2(&s1h[p][c][q * 8], &s1l[p][c][q * 8], aR, aZ, a4, W2h, W2l);
      }
      epi(pn, false, 0);
    }
    if (doX) {
      uint16_t hh, hl; split2(xpre, hh, hl);
      s0h[pn][xm][64 + xi] = hh; s0l[pn][xm][64 + xi] = hl;
    }
    __syncthreads();
  }
  // state: h0(255) in s0[0] & A.hr; h1(255) in s1[1] & B.hr

  // ============================ decoder weights + preamble ============================
  ob = outB[0];
  if (isA) {
    loadW64(dWhh0);
    // W2 = rank-1 head fold: W'[n][k] = dWih0[n] * outW[k]
    #pragma unroll
    for (int s = 0; s < 3; s++) {
      const int n = (s * 4 + wvL) * 16 + c;
      const float wd = dWih0[n];
      #pragma unroll
      for (int kt = 0; kt < 2; kt++) {
        const int k0 = kt * 32 + q * 8;
        #pragma unroll
        for (int j = 0; j < 8; j++) {
          uint16_t h, l; split2(wd * outW[k0 + j], h, l);
          W2h[s][kt][j] = (short)h; W2l[s][kt][j] = (short)l;
        }
      }
    }
    const float fo_r = dWih0[u] * ob, fo_z = dWih0[64 + u] * ob, fo_n = dWih0[128 + u] * ob;
    const float b_r = dbih0[u] + dbhh0[u], b_z = dbih0[64 + u] + dbhh0[64 + u];
    const float b3 = dbhh0[128 + u], b4 = dbih0[128 + u];
    cR = b_r + fo_r; cZ = b_z + fo_z; c3 = b3; c4 = b4 + fo_n;  // steady-state consts (fold ob)
    // preamble: src1-pass for decoder step 0 (prev=0 -> base consts, no fold-ob)
    aR = (floatx4){b_r, b_r, b_r, b_r}; aZ = (floatx4){b_z, b_z, b_z, b_z};
    a3 = (floatx4){b3, b3, b3, b3};     a4 = (floatx4){b4, b4, b4, b4};
    PASS2(&s0h[0][c][q * 8], &s0l[0][c][q * 8], aR, aZ, a3, W1h, W1l);
  } else {
    loadW64(dWih1); loadW64b(dWhh1);
    cR = dbih1[u] + dbhh1[u];
    cZ = dbih1[64 + u] + dbhh1[64 + u];
    c3 = dbih1[128 + u]; c4 = dbhh1[128 + u];
    woutr = outW[u];
  }

  // ============================ decoder: 2-phase overlapped ============================
  for (int d = 0; d < TDEC; d++) {
    const int pw = (d + 1) & 1;   // s0 parity receiving h0d(d)
    const int q2 = (d & 1) ^ 1;   // s1 parity holding h1d(d-1)
    // ---- phase alpha: A folds h1d(d-1) + finishes h0d(d);  B: hh-partials ----
    if (!isA) {
      aR = (floatx4){cR, cR, cR, cR}; aZ = (floatx4){cZ, cZ, cZ, cZ};
      a3 = (floatx4){c3, c3, c3, c3}; a4 = (floatx4){c4, c4, c4, c4};
      PASS2(&s1h[q2][c][q * 8], &s1l[q2][c][q * 8], aR, aZ, a4, W2h, W2l);
    } else {
      if (d > 0) {
        PASS2(&s1h[q2][c][q * 8], &s1l[q2][c][q * 8], aR, aZ, a4, W2h, W2l);
      }
      epi(pw, false, 0);
      if (tid < GROWS && d > 0) {  // off-critical-path head store for step d-1
        const int pc = (d - 1) & 1;
        out[(base + tid) * TDEC + (d - 1)] =
            ob + cvp[pc][tid][0] + cvp[pc][tid][1] + cvp[pc][tid][2] + cvp[pc][tid][3];
      }
    }
    __syncthreads();
    // ---- phase beta: B finishes h1d(d) + writes; A pre-computes Whh0.h0d(d) for step d+1 ----
    if (isA) {
      if (d < TDEC - 1) {
        aR = (floatx4){cR, cR, cR, cR}; aZ = (floatx4){cZ, cZ, cZ, cZ};
        a3 = (floatx4){c3, c3, c3, c3}; a4 = (floatx4){c4, c4, c4, c4};
        PASS2(&s0h[pw][c][q * 8], &s0l[pw][c][q * 8], aR, aZ, a3, W1h, W1l);
      }
    } else {
      PASS2(&s0h[pw][c][q * 8], &s0l[pw][c][q * 8], aR, aZ, a3, W1h, W1l);
      epi(d & 1, true, d & 1);
    }
    __syncthreads();
  }
  if (tid < GROWS) {
    const int pc = (TDEC - 1) & 1;
    out[(base + tid) * TDEC + (TDEC - 1)] =
        ob + cvp[pc][tid][0] + cvp[pc][tid][1] + cvp[pc][tid][2] + cvp[pc][tid][3];
  }
}

extern "C" void kernel_launch(void* const* d_in, const int* in_sizes, int n_in,
                              void* d_out, int out_size, void* d_ws, size_t ws_size,
                              hipStream_t stream) {
  (void)in_sizes; (void)n_in; (void)d_ws; (void)ws_size; (void)out_size;
  const float* x     = (const float*)d_in[0];
  const float* eWih0 = (const float*)d_in[1];
  const float* eWhh0 = (const float*)d_in[2];
  const float* ebih0 = (const float*)d_in[3];
  const float* ebhh0 = (const float*)d_in[4];
  const float* eWih1 = (const float*)d_in[5];
  const float* eWhh1 = (const float*)d_in[6];
  const float* ebih1 = (const float*)d_in[7];
  const float* ebhh1 = (const float*)d_in[8];
  const float* dWih0 = (const float*)d_in[9];
  const float* dWhh0 = (const float*)d_in[10];
  const float* dbih0 = (const float*)d_in[11];
  const float* dbhh0 = (const float*)d_in[12];
  const float* dWih1 = (const float*)d_in[13];
  const float* dWhh1 = (const float*)d_in[14];
  const float* dbih1 = (const float*)d_in[15];
  const float* dbhh1 = (const float*)d_in[16];
  const float* outW  = (const float*)d_in[17];
  const float* outB  = (const float*)d_in[18];
  hipLaunchKernelGGL(gru_persist, dim3(NBLK), dim3(512), 0, stream,
                     x, eWih0, eWhh0, ebih0, ebhh0, eWih1, eWhh1, ebih1, ebhh1,
                     dWih0, dWhh0, dbih0, dbhh0, dWih1, dWhh1, dbih1, dbhh1,
                     outW, outB, (float*)d_out);
}

// Round 4
// 620.743 us; speedup vs baseline: 2.2382x; 1.0849x over previous
//
#include <hip/hip_runtime.h>
#include <cstdint>

typedef __attribute__((ext_vector_type(8))) short short8;
typedef __attribute__((ext_vector_type(4))) float floatx4;
typedef unsigned int uint;

#define TSEQ 256
#define TDEC 180
#define NIN  6
#define GROWS 16
#define NBLK (4096 / GROWS)
#define RS0 104   // s0 row stride (shorts): cols 0..63 h0, 64..95 x|0, 96..103 pad
#define RS1 72    // s1 row stride

// split fp32 into hi/lo bf16 (truncation): x ~= hi + lo, err ~2^-16*|x|
__device__ __forceinline__ void split2(float x, uint16_t &h, uint16_t &l) {
  uint32_t u = __float_as_uint(x);
  h = (uint16_t)(u >> 16);
  float hf = __uint_as_float(u & 0xffff0000u);
  l = (uint16_t)(__float_as_uint(x - hf) >> 16);
}

__device__ __forceinline__ floatx4 mfma16(short8 a, short8 b, floatx4 c) {
  return __builtin_amdgcn_mfma_f32_16x16x32_bf16(a, b, c, 0, 0, 0);
}

__device__ __forceinline__ float sigm(float v) {
  return __builtin_amdgcn_rcpf(1.0f + __builtin_amdgcn_exp2f(-1.4426950408889634f * v));
}
__device__ __forceinline__ float tanh_fast(float v) {
  return 2.0f * __builtin_amdgcn_rcpf(1.0f + __builtin_amdgcn_exp2f(-2.8853900817779268f * v)) - 1.0f;
}

// 2-ktile 3-acc split-bf16 pass from LDS pointers
#define PASS2(SH, SL, r, z, g, Wh, Wl) do {                                              \
    _Pragma("unroll")                                                                    \
    for (int kt_ = 0; kt_ < 2; kt_++) {                                                  \
      const short8 ah_ = *(const short8*)((SH) + kt_ * 32);                              \
      const short8 al_ = *(const short8*)((SL) + kt_ * 32);                              \
      r = mfma16(ah_, (Wh)[0][kt_], r); z = mfma16(ah_, (Wh)[1][kt_], z); g = mfma16(ah_, (Wh)[2][kt_], g); \
      r = mfma16(al_, (Wh)[0][kt_], r); z = mfma16(al_, (Wh)[1][kt_], z); g = mfma16(al_, (Wh)[2][kt_], g); \
      r = mfma16(ah_, (Wl)[0][kt_], r); z = mfma16(ah_, (Wl)[1][kt_], z); g = mfma16(ah_, (Wl)[2][kt_], g); \
    } } while (0)

#define PASS1(SH, SL, r, z, g, Wh, Wl) do {                                              \
      const short8 ah_ = *(const short8*)(SH);                                           \
      const short8 al_ = *(const short8*)(SL);                                           \
      r = mfma16(ah_, (Wh)[0][0], r); z = mfma16(ah_, (Wh)[1][0], z); g = mfma16(ah_, (Wh)[2][0], g); \
      r = mfma16(al_, (Wh)[0][0], r); z = mfma16(al_, (Wh)[1][0], z); g = mfma16(al_, (Wh)[2][0], g); \
      r = mfma16(ah_, (Wl)[0][0], r); z = mfma16(ah_, (Wl)[1][0], z); g = mfma16(ah_, (Wl)[2][0], g); \
    } while (0)

// same but from pre-read fragments (B keeps them for the head dot)
#define PASS2F(F0H, F0L, F1H, F1L, r, z, g, Wh, Wl) do {                                 \
      r = mfma16(F0H, (Wh)[0][0], r); z = mfma16(F0H, (Wh)[1][0], z); g = mfma16(F0H, (Wh)[2][0], g); \
      r = mfma16(F0L, (Wh)[0][0], r); z = mfma16(F0L, (Wh)[1][0], z); g = mfma16(F0L, (Wh)[2][0], g); \
      r = mfma16(F0H, (Wl)[0][0], r); z = mfma16(F0H, (Wl)[1][0], z); g = mfma16(F0H, (Wl)[2][0], g); \
      r = mfma16(F1H, (Wh)[0][1], r); z = mfma16(F1H, (Wh)[1][1], z); g = mfma16(F1H, (Wh)[2][1], g); \
      r = mfma16(F1L, (Wh)[0][1], r); z = mfma16(F1L, (Wh)[1][1], z); g = mfma16(F1L, (Wh)[2][1], g); \
      r = mfma16(F1H, (Wl)[0][1], r); z = mfma16(F1H, (Wl)[1][1], z); g = mfma16(F1H, (Wl)[2][1], g); \
    } while (0)

__device__ __forceinline__ void pollge(const volatile uint* p4, uint need) {
  for (;;) {
    uint a = p4[0], b = p4[1], cc = p4[2], d = p4[3];
    uint m = a < b ? a : b, n = cc < d ? cc : d, mn = m < n ? m : n;
    if (mn >= need) break;
    __builtin_amdgcn_s_sleep(1);
  }
  asm volatile("" ::: "memory");   // no hoisting of data reads above the poll
}

__global__ void __launch_bounds__(512, 2)
gru_persist(const float* __restrict__ x,
            const float* __restrict__ eWih0, const float* __restrict__ eWhh0,
            const float* __restrict__ ebih0, const float* __restrict__ ebhh0,
            const float* __restrict__ eWih1, const float* __restrict__ eWhh1,
            const float* __restrict__ ebih1, const float* __restrict__ ebhh1,
            const float* __restrict__ dWih0, const float* __restrict__ dWhh0,
            const float* __restrict__ dbih0, const float* __restrict__ dbhh0,
            const float* __restrict__ dWih1, const float* __restrict__ dWhh1,
            const float* __restrict__ dbih1, const float* __restrict__ dbhh1,
            const float* __restrict__ outW, const float* __restrict__ outB,
            float* __restrict__ out)
{
  __shared__ __align__(16) uint16_t s0h[2][16][RS0], s0l[2][16][RS0];
  __shared__ __align__(16) uint16_t s1h[2][16][RS1], s1l[2][16][RS1];
  __shared__ __align__(16) uint prog[8];   // [0..3]=A waves, [4..7]=B waves

  const int tid  = threadIdx.x;
  const bool isA = tid < 256;          // A = layer0 waves, B = layer1 waves
  const int wvL  = (tid >> 6) & 3;
  const int lane = tid & 63;
  const int c    = lane & 15;
  const int q    = lane >> 4;
  const int u    = wvL * 16 + c;
  const long base = (long)blockIdx.x * GROWS;

  const volatile uint* aprog = (const volatile uint*)&prog[0];
  const volatile uint* bprog = (const volatile uint*)&prog[4];
  volatile uint* myslot = (volatile uint*)&prog[(isA ? 0 : 4) + wvL];

  for (int i = tid; i < 2 * 16 * RS0; i += 512) { ((uint16_t*)s0h)[i] = 0; ((uint16_t*)s0l)[i] = 0; }
  for (int i = tid; i < 2 * 16 * RS1; i += 512) { ((uint16_t*)s1h)[i] = 0; ((uint16_t*)s1l)[i] = 0; }
  if (tid < 8) prog[tid] = 0;
  if (tid < GROWS * NIN) {  // x(0) -> s0[0]
    int m = tid / 6, i2 = tid - m * 6;
    uint16_t h, l; split2(x[(base + m) * (TSEQ * NIN) + i2], h, l);
    s0h[0][m][64 + i2] = h; s0l[0][m][64 + i2] = l;
  }

  short8 W1h[3][2], W1l[3][2];   // A: Whh0 | B: Wih1
  short8 W2h[3][2], W2l[3][2];   // A: [Wih0|0] (enc) / rank-1 fold (dec) | B: Whh1
  float hr[4] = {0, 0, 0, 0};

  auto loadW64 = [&](const float* W, short8 (&Dh)[3][2], short8 (&Dl)[3][2]) {
    #pragma unroll
    for (int s = 0; s < 3; s++) {
      const int n = (s * 4 + wvL) * 16 + c;
      #pragma unroll
      for (int kt = 0; kt < 2; kt++) {
        const int k0 = kt * 32 + q * 8;
        #pragma unroll
        for (int j = 0; j < 8; j++) {
          uint16_t h, l; split2(W[n * 64 + k0 + j], h, l);
          Dh[s][kt][j] = (short)h; Dl[s][kt][j] = (short)l;
        }
      }
    }
  };

  float cR, cZ, c3, c4;
  if (isA) {
    loadW64(eWhh0, W1h, W1l);
    #pragma unroll
    for (int s = 0; s < 3; s++) {
      const int n = (s * 4 + wvL) * 16 + c;
      #pragma unroll
      for (int kt = 0; kt < 2; kt++)
        #pragma unroll
        for (int j = 0; j < 8; j++) {
          float v = (kt == 0 && q == 0 && j < NIN) ? eWih0[n * NIN + j] : 0.0f;
          uint16_t h, l; split2(v, h, l);
          W2h[s][kt][j] = (short)h; W2l[s][kt][j] = (short)l;
        }
    }
    cR = ebih0[u] + ebhh0[u];
    cZ = ebih0[64 + u] + ebhh0[64 + u];
    c3 = ebhh0[128 + u];   // gh const (src1 = Whh0)
    c4 = ebih0[128 + u];   // gi const (src2 = x)
  } else {
    loadW64(eWih1, W1h, W1l); loadW64(eWhh1, W2h, W2l);
    cR = ebih1[u] + ebhh1[u];
    cZ = ebih1[64 + u] + ebhh1[64 + u];
    c3 = ebih1[128 + u];   // gi const (src1 = Wih1)
    c4 = ebhh1[128 + u];   // gh const (src2 = Whh1)
  }
  __syncthreads();   // last barrier: everything after uses the flag protocol

  if (isA) {
    // ---- x prefetch pipeline on wave A0, lanes 0..47, 2 slots each, depth 2 ----
    const bool doX = (wvL == 0) && (lane < 48);
    const float *px0 = nullptr, *px1 = nullptr;
    int xo0 = 0, xo1 = 0; float xn0 = 0.f, xn1 = 0.f;
    if (doX) {
      int s0_ = lane, s1_ = lane + 48;
      int m0 = s0_ / 6, i0 = s0_ - m0 * 6, m1 = s1_ / 6, i1 = s1_ - m1 * 6;
      px0 = x + (base + m0) * (TSEQ * NIN) + i0;
      px1 = x + (base + m1) * (TSEQ * NIN) + i1;
      xo0 = m0 * RS0 + 64 + i0; xo1 = m1 * RS0 + 64 + i1;
      xn0 = px0[NIN]; xn1 = px1[NIN];   // x(1)
    }
    // ================= encoder =================
    for (int i = 0; i < TSEQ; i += 2) {
      #pragma unroll
      for (int h2 = 0; h2 < 2; h2++) {
        const int i_ = i + h2, p = h2, pn = h2 ^ 1;
        pollge(aprog, (uint)i_);                       // peers done step i_-1 (incl. x(i_))
        floatx4 aR = {cR, cR, cR, cR}, aZ = {cZ, cZ, cZ, cZ};
        floatx4 a3 = {c3, c3, c3, c3}, a4 = {c4, c4, c4, c4};
        PASS2(&s0h[p][c][q * 8], &s0l[p][c][q * 8], aR, aZ, a3, W1h, W1l);
        PASS1(&s0h[p][c][64 + q * 8], &s0l[p][c][64 + q * 8], aR, aZ, a4, W2h, W2l);
        pollge(bprog, (uint)(i_ > 0 ? i_ - 1 : 0));    // WAR: B consumed s0[pn] generation-2
        if (doX && i_ + 1 < TSEQ) {
          uint16_t hh, hl;
          split2(xn0, hh, hl); s0h[pn][0][xo0] = hh; s0l[pn][0][xo0] = hl;
          split2(xn1, hh, hl); s0h[pn][0][xo1] = hh; s0l[pn][0][xo1] = hl;
          if (i_ + 2 < TSEQ) { xn0 = px0[(i_ + 2) * NIN]; xn1 = px1[(i_ + 2) * NIN]; }
        }
        #pragma unroll
        for (int r4 = 0; r4 < 4; r4++) {
          const float gr = sigm(aR[r4]);
          const float gz = sigm(aZ[r4]);
          const float nn = tanh_fast(a4[r4] + gr * a3[r4]);
          const float hn = nn + gz * (hr[r4] - nn);
          hr[r4] = hn;
          uint16_t hh, hl; split2(hn, hh, hl);
          s0h[pn][q * 4 + r4][u] = hh; s0l[pn][q * 4 + r4][u] = hl;
        }
        asm volatile("s_waitcnt lgkmcnt(0)" ::: "memory");
        *myslot = (uint)(i_ + 1);
      }
    }
    // ================= decoder weights (fold) =================
    loadW64(dWhh0, W1h, W1l);
    const float ob = outB[0];
    #pragma unroll
    for (int s = 0; s < 3; s++) {
      const int n = (s * 4 + wvL) * 16 + c;
      const float wd = dWih0[n];
      #pragma unroll
      for (int kt = 0; kt < 2; kt++) {
        const int k0 = kt * 32 + q * 8;
        #pragma unroll
        for (int j = 0; j < 8; j++) {
          uint16_t h, l; split2(wd * outW[k0 + j], h, l);
          W2h[s][kt][j] = (short)h; W2l[s][kt][j] = (short)l;
        }
      }
    }
    const float bR0 = dbih0[u] + dbhh0[u];
    const float bZ0 = dbih0[64 + u] + dbhh0[64 + u];
    const float b30 = dbhh0[128 + u];
    const float b40 = dbih0[128 + u];
    cR = bR0 + dWih0[u] * ob;
    cZ = bZ0 + dWih0[64 + u] * ob;
    c3 = b30;
    c4 = b40 + dWih0[128 + u] * ob;
    // ================= decoder =================
    for (int i = TSEQ; i < TSEQ + TDEC; i += 2) {
      #pragma unroll
      for (int h2 = 0; h2 < 2; h2++) {
        const int i_ = i + h2, p = h2, pn = h2 ^ 1;
        const bool first = (i_ == TSEQ);
        pollge(aprog, (uint)i_);
        const float vR = first ? bR0 : cR, vZ = first ? bZ0 : cZ, v4 = first ? b40 : c4;
        floatx4 aR = {vR, vR, vR, vR}, aZ = {vZ, vZ, vZ, vZ};
        floatx4 a3 = {c3, c3, c3, c3}, a4 = {v4, v4, v4, v4};
        PASS2(&s0h[p][c][q * 8], &s0l[p][c][q * 8], aR, aZ, a3, W1h, W1l);   // Whh0.h0 -> gh
        pollge(bprog, (uint)(first ? i_ - 1 : i_));
        if (!first) {   // rank-1 head fold: W'.h1(d-1) -> r,z,gi
          PASS2(&s1h[p][c][q * 8], &s1l[p][c][q * 8], aR, aZ, a4, W2h, W2l);
        }
        #pragma unroll
        for (int r4 = 0; r4 < 4; r4++) {
          const float gr = sigm(aR[r4]);
          const float gz = sigm(aZ[r4]);
          const float nn = tanh_fast(a4[r4] + gr * a3[r4]);
          const float hn = nn + gz * (hr[r4] - nn);
          hr[r4] = hn;
          uint16_t hh, hl; split2(hn, hh, hl);
          s0h[pn][q * 4 + r4][u] = hh; s0l[pn][q * 4 + r4][u] = hl;
        }
        asm volatile("s_waitcnt lgkmcnt(0)" ::: "memory");
        *myslot = (uint)(i_ + 1);
      }
    }
  } else {
    // =========================== group B: layer 1 ===========================
    const float ob = outB[0];
    float wk[2][8];
    #pragma unroll
    for (int kt = 0; kt < 2; kt++)
      #pragma unroll
      for (int j = 0; j < 8; j++) wk[kt][j] = outW[kt * 32 + q * 8 + j];

    for (int i = 0; i < TSEQ; i += 2) {
      #pragma unroll
      for (int h2 = 0; h2 < 2; h2++) {
        const int i_ = i + h2, p = h2, pn = h2 ^ 1;
        pollge(bprog, (uint)i_);                       // peers' h1(i_-1)
        const short8 f0h = *(const short8*)&s1h[p][c][q * 8];
        const short8 f0l = *(const short8*)&s1l[p][c][q * 8];
        const short8 f1h = *(const short8*)&s1h[p][c][32 + q * 8];
        const short8 f1l = *(const short8*)&s1l[p][c][32 + q * 8];
        floatx4 aR = {cR, cR, cR, cR}, aZ = {cZ, cZ, cZ, cZ};
        floatx4 a3 = {c3, c3, c3, c3}, a4 = {c4, c4, c4, c4};
        PASS2F(f0h, f0l, f1h, f1l, aR, aZ, a4, W2h, W2l);   // Whh1.h1 -> gh
        pollge(aprog, (uint)(i_ + 1));                 // h0(i_) ready
        PASS2(&s0h[pn][c][q * 8], &s0l[pn][c][q * 8], aR, aZ, a3, W1h, W1l);  // Wih1.h0 -> gi
        #pragma unroll
        for (int r4 = 0; r4 < 4; r4++) {
          const float gr = sigm(aR[r4]);
          const float gz = sigm(aZ[r4]);
          const float nn = tanh_fast(a3[r4] + gr * a4[r4]);
          const float hn = nn + gz * (hr[r4] - nn);
          hr[r4] = hn;
          uint16_t hh, hl; split2(hn, hh, hl);
          s1h[pn][q * 4 + r4][u] = hh; s1l[pn][q * 4 + r4][u] = hl;
        }
        asm volatile("s_waitcnt lgkmcnt(0)" ::: "memory");
        *myslot = (uint)(i_ + 1);
      }
    }
    loadW64(dWih1, W1h, W1l); loadW64(dWhh1, W2h, W2l);
    cR = dbih1[u] + dbhh1[u];
    cZ = dbih1[64 + u] + dbhh1[64 + u];
    c3 = dbih1[128 + u]; c4 = dbhh1[128 + u];
    for (int i = TSEQ; i < TSEQ + TDEC; i += 2) {
      #pragma unroll
      for (int h2 = 0; h2 < 2; h2++) {
        const int i_ = i + h2, p = h2, pn = h2 ^ 1;
        pollge(bprog, (uint)i_);
        const short8 f0h = *(const short8*)&s1h[p][c][q * 8];
        const short8 f0l = *(const short8*)&s1l[p][c][q * 8];
        const short8 f1h = *(const short8*)&s1h[p][c][32 + q * 8];
        const short8 f1l = *(const short8*)&s1l[p][c][32 + q * 8];
        floatx4 aR = {cR, cR, cR, cR}, aZ = {cZ, cZ, cZ, cZ};
        floatx4 a3 = {c3, c3, c3, c3}, a4 = {c4, c4, c4, c4};
        PASS2F(f0h, f0l, f1h, f1l, aR, aZ, a4, W2h, W2l);   // Whh1.h1 -> gh
        if (wvL == 0 && i_ > TSEQ) {   // head: cv(d) from h1(i_-1) fragments (off critical path)
          float cv = 0.0f;
          #pragma unroll
          for (int j = 0; j < 8; j++) {
            cv = fmaf(__uint_as_float(((uint)(uint16_t)f0h[j]) << 16) +
                      __uint_as_float(((uint)(uint16_t)f0l[j]) << 16), wk[0][j], cv);
            cv = fmaf(__uint_as_float(((uint)(uint16_t)f1h[j]) << 16) +
                      __uint_as_float(((uint)(uint16_t)f1l[j]) << 16), wk[1][j], cv);
          }
          cv += __shfl_xor(cv, 16);
          cv += __shfl_xor(cv, 32);
          if (lane < 16) out[(base + lane) * TDEC + (i_ - TSEQ - 1)] = cv + ob;
        }
        pollge(aprog, (uint)(i_ + 1));
        PASS2(&s0h[pn][c][q * 8], &s0l[pn][c][q * 8], aR, aZ, a3, W1h, W1l);  // Wih1.h0 -> gi
        #pragma unroll
        for (int r4 = 0; r4 < 4; r4++) {
          const float gr = sigm(aR[r4]);
          const float gz = sigm(aZ[r4]);
          const float nn = tanh_fast(a3[r4] + gr * a4[r4]);
          const float hn = nn + gz * (hr[r4] - nn);
          hr[r4] = hn;
          uint16_t hh, hl; split2(hn, hh, hl);
          s1h[pn][q * 4 + r4][u] = hh; s1l[pn][q * 4 + r4][u] = hl;
        }
        asm volatile("s_waitcnt lgkmcnt(0)" ::: "memory");
        *myslot = (uint)(i_ + 1);
      }
    }
    // final head value: cv(179) from h1(435) in s1[0]
    if (wvL == 0) {
      pollge(bprog, (uint)(TSEQ + TDEC));
      const short8 f0h = *(const short8*)&s1h[0][c][q * 8];
      const short8 f0l = *(const short8*)&s1l[0][c][q * 8];
      const short8 f1h = *(const short8*)&s1h[0][c][32 + q * 8];
      const short8 f1l = *(const short8*)&s1l[0][c][32 + q * 8];
      float cv = 0.0f;
      #pragma unroll
      for (int j = 0; j < 8; j++) {
        cv = fmaf(__uint_as_float(((uint)(uint16_t)f0h[j]) << 16) +
                  __uint_as_float(((uint)(uint16_t)f0l[j]) << 16), wk[0][j], cv);
        cv = fmaf(__uint_as_float(((uint)(uint16_t)f1h[j]) << 16) +
                  __uint_as_float(((uint)(uint16_t)f1l[j]) << 16), wk[1][j], cv);
      }
      cv += __shfl_xor(cv, 16);
      cv += __shfl_xor(cv, 32);
      if (lane < 16) out[(base + lane) * TDEC + (TDEC - 1)] = cv + ob;
    }
  }
}

extern "C" void kernel_launch(void* const* d_in, const int* in_sizes, int n_in,
                              void* d_out, int out_size, void* d_ws, size_t ws_size,
                              hipStream_t stream) {
  (void)in_sizes; (void)n_in; (void)d_ws; (void)ws_size; (void)out_size;
  const float* x     = (const float*)d_in[0];
  const float* eWih0 = (const float*)d_in[1];
  const float* eWhh0 = (const float*)d_in[2];
  const float* ebih0 = (const float*)d_in[3];
  const float* ebhh0 = (const float*)d_in[4];
  const float* eWih1 = (const float*)d_in[5];
  const float* eWhh1 = (const float*)d_in[6];
  const float* ebih1 = (const float*)d_in[7];
  const float* ebhh1 = (const float*)d_in[8];
  const float* dWih0 = (const float*)d_in[9];
  const float* dWhh0 = (const float*)d_in[10];
  const float* dbih0 = (const float*)d_in[11];
  const float* dbhh0 = (const float*)d_in[12];
  const float* dWih1 = (const float*)d_in[13];
  const float* dWhh1 = (const float*)d_in[14];
  const float* dbih1 = (const float*)d_in[15];
  const float* dbhh1 = (const float*)d_in[16];
  const float* outW  = (const float*)d_in[17];
  const float* outB  = (const float*)d_in[18];
  hipLaunchKernelGGL(gru_persist, dim3(NBLK), dim3(512), 0, stream,
                     x, eWih0, eWhh0, ebih0, ebhh0, eWih1, eWhh1, ebih1, ebhh1,
                     dWih0, dWhh0, dbih0, dbhh0, dWih1, dWhh1, dbih1, dbhh1,
                     outW, outB, (float*)d_out);
}